// Round 9
// baseline (353.558 us; speedup 1.0000x reference)
//
#include <hip/hip_runtime.h>

// FilterInitializerLinear: conv3x3(512->512, pad1) on (192,512,22,22) fp32,
// PrRoIPool 4x4 per (image,seq) roi, mean over 3 images, /(C*16).
// KEY ALGEBRA: pooling and conv are both linear -> pool FIRST:
//   out[s,co,pq] = (sum_K W[co,K] * G[s,K,pq] + b[co]*Sy[p]*Sx[q]) / (3*512*16)
//   G[ci,ky,kx,p,q] = sum_{u,v} wy_shift[ky][p][u] * wx_shift[kx][q][v] * F[ci][u][v]
// Matmul shrinks 114 GFLOP -> 4.8 GFLOP (N: 24k -> 64 seq * 16 bins).

#define NIMG 192
#define CCH 512
#define FH 22
#define FW 22
#define SPATIAL 484
#define KDIM 4608          // pos*512 + ci
#define NDIM 1024          // s*16 + p*4 + q
#define KQ 8               // K-split factor in GEMM
#define KSEG 576           // KDIM / KQ

typedef __bf16 bf16;
typedef __bf16 bf16x2 __attribute__((ext_vector_type(2)));
typedef __bf16 bf16x8 __attribute__((ext_vector_type(8)));
typedef float f32x4 __attribute__((ext_vector_type(4)));

#define GLOBAL_AS __attribute__((address_space(1)))
#define LDS_AS __attribute__((address_space(3)))

__device__ __forceinline__ void gload_lds16(const void* g, void* l) {
  __builtin_amdgcn_global_load_lds((GLOBAL_AS const void*)g, (LDS_AS void*)l, 16, 0, 0);
}

// ---- prep (1 block): shifted pooling-weight tables wys_g/wxs_g[n][ky][u][p]
// (fp32, zero-padded shifts), per-image read ranges boxes[n] = {yr0,yr1,xr0,xr1},
// bias factors BF[s][16] = sum_i Sy[p]*Sx[q].
__global__ __launch_bounds__(256) void prep_kernel(const float* __restrict__ bb,
                                                   int* __restrict__ boxes,
                                                   float* __restrict__ wys_g,
                                                   float* __restrict__ wxs_g,
                                                   float* __restrict__ BF) {
  __shared__ float syl[NIMG][2][4];
  int t = threadIdx.x;
  const float scale = 1.f / 16.f;
  // zero both shifted tables (contiguous in ws: wys_g then wxs_g, 101376 floats)
  f32x4* z = (f32x4*)wys_g;
  for (int idx = t; idx < 25344; idx += 256) z[idx] = (f32x4){0.f, 0.f, 0.f, 0.f};
  if (t < NIMG) {
    int n = t;
    float x1s = bb[n * 4 + 0] * scale;
    float y1s = bb[n * 4 + 1] * scale;
    float x2s = (bb[n * 4 + 0] + bb[n * 4 + 2]) * scale;
    float y2s = (bb[n * 4 + 1] + bb[n * 4 + 3]) * scale;
    float binx = (x2s - x1s) * 0.25f;
    float biny = (y2s - y1s) * 0.25f;
    float endx = (x1s + 3 * binx) + binx;   // fp-identical to weight-fill bin-3 end
    float endy = (y1s + 3 * biny) + biny;
    int x0 = max(0, (int)floorf(x1s));
    int xc1 = min(FW - 1, (int)floorf(endx) + 1);
    int y0 = max(0, (int)floorf(y1s));
    int yc1 = min(FH - 1, (int)floorf(endy) + 1);
    int* b = boxes + n * 4;
    b[0] = max(0, y0 - 1);       // u-range (support of shifted wy)
    b[1] = min(FH - 1, yc1 + 1);
    b[2] = max(0, x0 - 1);       // v-range
    b[3] = min(FW - 1, xc1 + 1);
  }
  __syncthreads();
  // weight fill: item = (n, axis, p); each item owns distinct table entries
  #pragma unroll
  for (int k = 0; k < 6; ++k) {
    int item = t + 256 * k;   // < 1536
    int n = item >> 3;
    int axis = (item >> 2) & 1;
    int p = item & 3;
    float a0 = axis ? bb[n * 4 + 0] : bb[n * 4 + 1];
    float aw = axis ? bb[n * 4 + 2] : bb[n * 4 + 3];
    float s1 = a0 * scale;
    float s2 = (a0 + aw) * scale;
    float blen = (s2 - s1) * 0.25f;
    float start = s1 + p * blen;
    float end = start + blen;
    float inv = 1.0f / blen;           // folds 1/area
    float* tbl = (axis ? wxs_g : wys_g) + n * 264;   // [3ky][22u][4p]
    float S = 0.f;
    int s0i = (int)floorf(start);
    for (int kk = 0; kk < 6; ++kk) {
      int cell = s0i + kk;
      float cf = (float)cell;
      float a1 = fmaxf(start, cf);
      float a2 = fmaxf(fminf(end, cf + 1.f), a1);
      float alpha = a1 - cf, lim = a2 - cf;
      float f0 = (lim - 0.5f * lim * lim) - (alpha - 0.5f * alpha * alpha);
      float f1 = 0.5f * lim * lim - 0.5f * alpha * alpha;
      if (cell >= 0 && cell < 22) {
        float w = f0 * inv;
        S += w;
        #pragma unroll
        for (int ky = 0; ky < 3; ++ky) {
          int u = cell + ky - 1;
          if (u >= 0 && u < 22) tbl[(ky * 22 + u) * 4 + p] += w;
        }
      }
      if (cell + 1 >= 0 && cell + 1 < 22) {
        float w = f1 * inv;
        S += w;
        #pragma unroll
        for (int ky = 0; ky < 3; ++ky) {
          int u = cell + ky;
          if (u >= 0 && u < 22) tbl[(ky * 22 + u) * 4 + p] += w;
        }
      }
    }
    syl[n][axis][p] = S;
  }
  __syncthreads();
  #pragma unroll
  for (int k = 0; k < 4; ++k) {
    int item = t + 256 * k;   // < 1024 = s*16 + p*4 + q
    int s = item >> 4;
    int p = (item >> 2) & 3;
    int q = item & 3;
    float acc = 0.f;
    #pragma unroll
    for (int i = 0; i < 3; ++i)
      acc += syl[i * 64 + s][0][p] * syl[i * 64 + s][1][q];
    BF[item] = acc;
  }
}

// ---- cast: feat fp32 NCHW -> bf16 NHWC Ft[n][y][x][ci], restricted to the
// box read ranges. Fused: blocks [NIMG*FH, +CCH) do conv_w -> Wb[co][pos][ci].
__global__ __launch_bounds__(256) void cast_kernel(const float* __restrict__ feat,
                                                   bf16* __restrict__ Ft,
                                                   const float* __restrict__ cw,
                                                   bf16* __restrict__ Wb,
                                                   const int* __restrict__ boxes) {
  static __shared__ __align__(16) char smem[CCH * FW * 2];   // 22528 B
  int t = threadIdx.x;
  if (blockIdx.x >= NIMG * FH) {
    int co = blockIdx.x - NIMG * FH;
    float* lw = (float*)smem;
    const float* src = cw + (long)co * CCH * 9;
    #pragma unroll
    for (int k = 0; k < 18; ++k) lw[t + 256 * k] = src[t + 256 * k];
    __syncthreads();
    bf16* dst = Wb + (long)co * 9 * CCH;
    #pragma unroll
    for (int k = 0; k < 18; ++k) {
      int f = t + 256 * k;
      int pos = f >> 9;
      int ci = f & 511;
      dst[f] = (bf16)lw[ci * 9 + pos];
    }
    return;
  }
  bf16* lt = (bf16*)smem;   // [ci][x]
  int n = blockIdx.x / FH;
  int y = blockIdx.x % FH;
  int yr0 = boxes[n * 4 + 0], yr1 = boxes[n * 4 + 1];
  if (y < yr0 || y > yr1) return;
  int xr0 = boxes[n * 4 + 2], xr1 = boxes[n * 4 + 3];
  const float* fb = feat + (long)n * CCH * SPATIAL + y * FW;
  #pragma unroll 4
  for (int k = 0; k < 44; ++k) {            // 512*22 = 11264 = 256*44
    int f = t + 256 * k;
    int ci = f / FW;
    int x = f - ci * FW;
    if (x >= xr0 && x <= xr1) lt[f] = (bf16)fb[(long)ci * SPATIAL + x];
  }
  __syncthreads();
  uint* od = (uint*)(Ft + ((long)(n * FH + y) * FW) * CCH);
  int ci = t * 2;
  for (int px = xr0; px <= xr1; ++px) {
    bf16x2 pr;
    pr[0] = lt[ci * FW + px];
    pr[1] = lt[(ci + 1) * FW + px];
    od[px * 256 + t] = __builtin_bit_cast(uint, pr);
  }
}

// ---- pool_feat: separable PrRoI pooling of features (summed over 3 images).
// Gb[N=s*16+pq][K=pos*512+ci] bf16. Grid 256 = (s 64) x (ciq 4), 128 threads
// (thread = ci). Weight reads are wave-uniform -> scalar loads.
__global__ __launch_bounds__(128) void pool_feat_kernel(const bf16* __restrict__ Ft,
                                                        const int* __restrict__ boxes,
                                                        const float* __restrict__ wys_g,
                                                        const float* __restrict__ wxs_g,
                                                        bf16* __restrict__ Gb) {
  int s = blockIdx.x >> 2;
  int ciq = blockIdx.x & 3;
  int ci = ciq * 128 + threadIdx.x;
  f32x4 G4[9][4];   // [pos][p], vector over q
  #pragma unroll
  for (int a = 0; a < 9; ++a)
    #pragma unroll
    for (int b = 0; b < 4; ++b) G4[a][b] = (f32x4){0.f, 0.f, 0.f, 0.f};

  for (int i = 0; i < 3; ++i) {
    int n = i * 64 + s;
    int yr0 = boxes[n * 4 + 0], yr1 = boxes[n * 4 + 1];
    int xr0 = boxes[n * 4 + 2], xr1 = boxes[n * 4 + 3];
    const f32x4* wyp = (const f32x4*)(wys_g + n * 264);   // [ky*22+u] over p
    const f32x4* wxp = (const f32x4*)(wxs_g + n * 264);   // [kx*22+v] over q
    const bf16* fbase = Ft + (long)n * FH * FW * CCH + ci;
    for (int v = xr0; v <= xr1; ++v) {
      f32x4 ay0 = {0.f, 0.f, 0.f, 0.f};
      f32x4 ay1 = ay0, ay2 = ay0;
      const bf16* fp = fbase + v * CCH;
      for (int u = yr0; u <= yr1; ++u) {
        float f = (float)fp[u * (FW * CCH)];
        f32x4 w0 = wyp[u], w1 = wyp[22 + u], w2 = wyp[44 + u];
        ay0 += w0 * f;
        ay1 += w1 * f;
        ay2 += w2 * f;
      }
      #pragma unroll
      for (int kx = 0; kx < 3; ++kx) {
        f32x4 wx4 = wxp[kx * 22 + v];
        #pragma unroll
        for (int p = 0; p < 4; ++p) {
          G4[kx][p] += wx4 * ay0[p];
          G4[3 + kx][p] += wx4 * ay1[p];
          G4[6 + kx][p] += wx4 * ay2[p];
        }
      }
    }
  }
  // write: Gb[(s*16 + p*4 + q)*KDIM + pos*512 + ci]
  #pragma unroll
  for (int pos = 0; pos < 9; ++pos) {
    #pragma unroll
    for (int p = 0; p < 4; ++p) {
      #pragma unroll
      for (int q = 0; q < 4; ++q) {
        Gb[(long)(s * 16 + p * 4 + q) * KDIM + pos * CCH + ci] = (bf16)G4[pos][p][q];
      }
    }
  }
}

// ---- gemm: Opart[kq][co 512][n 1024] += W[co][k]*Gb[n][k] over k-segment.
// 256 blocks = 4 mt x 8 nt x 8 kq; 128x128 tile, 4 waves, BK=64, 9 chunks,
// proven staging + both-sides XOR swizzle.
__global__ __launch_bounds__(256, 2) void gemm_kernel(const bf16* __restrict__ Wb,
                                                      const bf16* __restrict__ Gb,
                                                      float* __restrict__ Opart) {
  __shared__ __align__(16) bf16 As[128 * 64];
  __shared__ __align__(16) bf16 Bs[128 * 64];
  int bid = blockIdx.x;
  int kq = bid & 7;
  int nt = (bid >> 3) & 7;
  int mt = bid >> 6;
  int co0 = mt << 7;
  int n0 = nt << 7;
  int kbase = kq * KSEG;

  int tid = threadIdx.x;
  int wv = tid >> 6, l = tid & 63;
  int wm = wv >> 1, wn = wv & 1;
  int lrow = l >> 3;
  int cg8 = ((l & 7) ^ lrow) << 3;

  long aOff[4], bOff[4];
  #pragma unroll
  for (int j = 0; j < 4; ++j) {
    int row = j * 32 + wv * 8 + lrow;
    aOff[j] = (long)(co0 + row) * KDIM + kbase + cg8;
    bOff[j] = (long)(n0 + row) * KDIM + kbase + cg8;
  }

  const f32x4 vz = {0.f, 0.f, 0.f, 0.f};
  f32x4 acc[4][4];
  #pragma unroll
  for (int a = 0; a < 4; ++a)
    #pragma unroll
    for (int b = 0; b < 4; ++b) acc[a][b] = vz;

  for (int c = 0; c < 9; ++c) {
    long sh = c * 64;
    #pragma unroll
    for (int j = 0; j < 4; ++j) {
      gload_lds16(Wb + aOff[j] + sh, (char*)As + (j * 32 + wv * 8) * 128);
      gload_lds16(Gb + bOff[j] + sh, (char*)Bs + (j * 32 + wv * 8) * 128);
    }
    __syncthreads();
    bf16x8 af[2][4], bfv[2][4];
    #pragma unroll
    for (int kk = 0; kk < 2; ++kk) {
      #pragma unroll
      for (int i = 0; i < 4; ++i) {
        int rowa = wm * 64 + i * 16 + (l & 15);
        int offa = rowa * 128 + kk * 64 + ((l >> 4) * 16);
        offa ^= (rowa & 7) << 4;
        af[kk][i] = *(const bf16x8*)((const char*)As + offa);
        int rowb = wn * 64 + i * 16 + (l & 15);
        int offb = rowb * 128 + kk * 64 + ((l >> 4) * 16);
        offb ^= (rowb & 7) << 4;
        bfv[kk][i] = *(const bf16x8*)((const char*)Bs + offb);
      }
    }
    #pragma unroll
    for (int kk = 0; kk < 2; ++kk)
      #pragma unroll
      for (int mi = 0; mi < 4; ++mi)
        #pragma unroll
        for (int nj = 0; nj < 4; ++nj)
          acc[mi][nj] = __builtin_amdgcn_mfma_f32_16x16x32_bf16(
              af[kk][mi], bfv[kk][nj], acc[mi][nj], 0, 0, 0);
    __syncthreads();
  }

  // C/D layout: col=lane&15 (n), row=(lane>>4)*4+reg (co)
  float* op = Opart + (long)kq * CCH * NDIM;
  #pragma unroll
  for (int nj = 0; nj < 4; ++nj) {
    int nn = n0 + wn * 64 + nj * 16 + (l & 15);
    #pragma unroll
    for (int mi = 0; mi < 4; ++mi) {
      #pragma unroll
      for (int rr = 0; rr < 4; ++rr) {
        int co = co0 + wm * 64 + mi * 16 + (l >> 4) * 4 + rr;
        op[(long)co * NDIM + nn] = acc[mi][nj][rr];
      }
    }
  }
}

// ---- epilogue: out[s][co][pq] = (sum_kq Opart + b[co]*BF[s][pq]) * fin
__global__ __launch_bounds__(256) void epi_kernel(const float* __restrict__ Opart,
                                                  const float* __restrict__ BF,
                                                  const float* __restrict__ cb,
                                                  float* __restrict__ out) {
  int t4 = blockIdx.x * 256 + threadIdx.x;   // 131072 threads, 4 floats each
  int base = t4 * 4;                         // = s*8192 + co*16 + pqc
  int s = base >> 13;
  int co = (base >> 4) & 511;
  int pqc = base & 15;
  long osrc = (long)co * NDIM + s * 16 + pqc;
  f32x4 v = *(const f32x4*)(Opart + osrc);
  #pragma unroll
  for (int kq = 1; kq < KQ; ++kq)
    v += *(const f32x4*)(Opart + (long)kq * CCH * NDIM + osrc);
  f32x4 bf4 = *(const f32x4*)(BF + s * 16 + pqc);
  const float fin = 1.f / (3.f * 512.f * 16.f);
  v = (v + cb[co] * bf4) * fin;
  *(f32x4*)(out + base) = v;
}

extern "C" void kernel_launch(void* const* d_in, const int* in_sizes, int n_in,
                              void* d_out, int out_size, void* d_ws, size_t ws_size,
                              hipStream_t stream) {
  const float* feat = (const float*)d_in[0];
  const float* bb = (const float*)d_in[1];
  const float* cw = (const float*)d_in[2];
  const float* cb = (const float*)d_in[3];
  float* out = (float*)d_out;

  const size_t FT_BYTES = (size_t)NIMG * FH * FW * CCH * 2;     //  95,158,272
  const size_t WB_BYTES = (size_t)CCH * 9 * CCH * 2;            //   4,718,592
  const size_t GB_BYTES = (size_t)NDIM * KDIM * 2;              //   9,437,184
  const size_t OP_BYTES = (size_t)KQ * CCH * NDIM * 4;          //  16,777,216
  const size_t WT_BYTES = (size_t)NIMG * 264 * 4;               //     202,752 (x2)
  const size_t BF_BYTES = 64 * 16 * 4;
  const size_t BOX_BYTES = NIMG * 4 * 4;
  if (ws_size < FT_BYTES + WB_BYTES + GB_BYTES + OP_BYTES + 2 * WT_BYTES +
                    BF_BYTES + BOX_BYTES)
    return;

  char* ws = (char*)d_ws;
  bf16* Ft = (bf16*)ws;
  bf16* Wb = (bf16*)(ws + FT_BYTES);
  bf16* Gb = (bf16*)(ws + FT_BYTES + WB_BYTES);
  float* Opart = (float*)(ws + FT_BYTES + WB_BYTES + GB_BYTES);
  float* wys_g = (float*)(ws + FT_BYTES + WB_BYTES + GB_BYTES + OP_BYTES);
  float* wxs_g = wys_g + NIMG * 264;
  float* BF = wxs_g + NIMG * 264;
  int* boxes = (int*)(BF + 64 * 16);

  hipLaunchKernelGGL(prep_kernel, dim3(1), dim3(256), 0, stream, bb, boxes, wys_g,
                     wxs_g, BF);
  hipLaunchKernelGGL(cast_kernel, dim3(NIMG * FH + CCH), dim3(256), 0, stream,
                     feat, Ft, cw, Wb, boxes);
  hipLaunchKernelGGL(pool_feat_kernel, dim3(256), dim3(128), 0, stream, Ft, boxes,
                     wys_g, wxs_g, Gb);
  hipLaunchKernelGGL(gemm_kernel, dim3(256), dim3(256), 0, stream, Wb, Gb, Opart);
  hipLaunchKernelGGL(epi_kernel, dim3(512), dim3(256), 0, stream, Opart, BF, cb, out);
}

// Round 10
// 331.650 us; speedup vs baseline: 1.0661x; 1.0661x over previous
//
#include <hip/hip_runtime.h>

// FilterInitializerLinear: conv3x3(512->512, pad1) on (192,512,22,22) fp32,
// PrRoIPool 4x4 per (image,seq) roi, mean over 3 images, /(C*16).
// KEY ALGEBRA: pooling and conv are both linear -> pool FIRST:
//   out[s,co,pq] = (sum_K W[co,K] * G[s,K,pq] + b[co]*Sy[p]*Sx[q]) / (3*512*16)
//   G[ci,ky,kx,p,q] = sum_{u,v} wy_shift[ky][p][u] * wx_shift[kx][q][v] * F[ci][u][v]
// Matmul shrinks 114 GFLOP -> 4.8 GFLOP. Round-9 fix: pool_feat thread=(ci,p)
// so per-thread acc is 36 floats (round 8's 144-float acc spilled to scratch).

#define NIMG 192
#define CCH 512
#define FH 22
#define FW 22
#define SPATIAL 484
#define KDIM 4608          // pos*512 + ci
#define NDIM 1024          // s*16 + p*4 + q
#define KQ 8               // K-split factor in GEMM
#define KSEG 576           // KDIM / KQ

typedef __bf16 bf16;
typedef __bf16 bf16x2 __attribute__((ext_vector_type(2)));
typedef __bf16 bf16x8 __attribute__((ext_vector_type(8)));
typedef float f32x4 __attribute__((ext_vector_type(4)));

#define GLOBAL_AS __attribute__((address_space(1)))
#define LDS_AS __attribute__((address_space(3)))

__device__ __forceinline__ void gload_lds16(const void* g, void* l) {
  __builtin_amdgcn_global_load_lds((GLOBAL_AS const void*)g, (LDS_AS void*)l, 16, 0, 0);
}

// ---- prep (1 block): shifted pooling-weight tables wys_g/wxs_g[n][ky][u][p]
// (fp32, zero-padded shifts), per-image read ranges boxes[n] = {yr0,yr1,xr0,xr1},
// bias factors BF[s][16] = sum_i Sy[p]*Sx[q].
__global__ __launch_bounds__(256) void prep_kernel(const float* __restrict__ bb,
                                                   int* __restrict__ boxes,
                                                   float* __restrict__ wys_g,
                                                   float* __restrict__ wxs_g,
                                                   float* __restrict__ BF) {
  __shared__ float syl[NIMG][2][4];
  int t = threadIdx.x;
  const float scale = 1.f / 16.f;
  // zero both shifted tables (contiguous in ws: wys_g then wxs_g, 101376 floats)
  f32x4* z = (f32x4*)wys_g;
  for (int idx = t; idx < 25344; idx += 256) z[idx] = (f32x4){0.f, 0.f, 0.f, 0.f};
  if (t < NIMG) {
    int n = t;
    float x1s = bb[n * 4 + 0] * scale;
    float y1s = bb[n * 4 + 1] * scale;
    float x2s = (bb[n * 4 + 0] + bb[n * 4 + 2]) * scale;
    float y2s = (bb[n * 4 + 1] + bb[n * 4 + 3]) * scale;
    float binx = (x2s - x1s) * 0.25f;
    float biny = (y2s - y1s) * 0.25f;
    float endx = (x1s + 3 * binx) + binx;   // fp-identical to weight-fill bin-3 end
    float endy = (y1s + 3 * biny) + biny;
    int x0 = max(0, (int)floorf(x1s));
    int xc1 = min(FW - 1, (int)floorf(endx) + 1);
    int y0 = max(0, (int)floorf(y1s));
    int yc1 = min(FH - 1, (int)floorf(endy) + 1);
    int* b = boxes + n * 4;
    b[0] = max(0, y0 - 1);       // u-range (support of shifted wy)
    b[1] = min(FH - 1, yc1 + 1);
    b[2] = max(0, x0 - 1);       // v-range
    b[3] = min(FW - 1, xc1 + 1);
  }
  __syncthreads();
  // weight fill: item = (n, axis, p); each item owns distinct table entries
  #pragma unroll
  for (int k = 0; k < 6; ++k) {
    int item = t + 256 * k;   // < 1536
    int n = item >> 3;
    int axis = (item >> 2) & 1;
    int p = item & 3;
    float a0 = axis ? bb[n * 4 + 0] : bb[n * 4 + 1];
    float aw = axis ? bb[n * 4 + 2] : bb[n * 4 + 3];
    float s1 = a0 * scale;
    float s2 = (a0 + aw) * scale;
    float blen = (s2 - s1) * 0.25f;
    float start = s1 + p * blen;
    float end = start + blen;
    float inv = 1.0f / blen;           // folds 1/area
    float* tbl = (axis ? wxs_g : wys_g) + n * 264;   // [3ky][22u][4p]
    float S = 0.f;
    int s0i = (int)floorf(start);
    for (int kk = 0; kk < 6; ++kk) {
      int cell = s0i + kk;
      float cf = (float)cell;
      float a1 = fmaxf(start, cf);
      float a2 = fmaxf(fminf(end, cf + 1.f), a1);
      float alpha = a1 - cf, lim = a2 - cf;
      float f0 = (lim - 0.5f * lim * lim) - (alpha - 0.5f * alpha * alpha);
      float f1 = 0.5f * lim * lim - 0.5f * alpha * alpha;
      if (cell >= 0 && cell < 22) {
        float w = f0 * inv;
        S += w;
        #pragma unroll
        for (int ky = 0; ky < 3; ++ky) {
          int u = cell + ky - 1;
          if (u >= 0 && u < 22) tbl[(ky * 22 + u) * 4 + p] += w;
        }
      }
      if (cell + 1 >= 0 && cell + 1 < 22) {
        float w = f1 * inv;
        S += w;
        #pragma unroll
        for (int ky = 0; ky < 3; ++ky) {
          int u = cell + ky;
          if (u >= 0 && u < 22) tbl[(ky * 22 + u) * 4 + p] += w;
        }
      }
    }
    syl[n][axis][p] = S;
  }
  __syncthreads();
  #pragma unroll
  for (int k = 0; k < 4; ++k) {
    int item = t + 256 * k;   // < 1024 = s*16 + p*4 + q
    int s = item >> 4;
    int p = (item >> 2) & 3;
    int q = item & 3;
    float acc = 0.f;
    #pragma unroll
    for (int i = 0; i < 3; ++i)
      acc += syl[i * 64 + s][0][p] * syl[i * 64 + s][1][q];
    BF[item] = acc;
  }
}

// ---- cast: feat fp32 NCHW -> bf16 NHWC Ft[n][y][x][ci], restricted to the
// box read ranges. Fused: blocks [NIMG*FH, +CCH) do conv_w -> Wb[co][pos][ci].
__global__ __launch_bounds__(256) void cast_kernel(const float* __restrict__ feat,
                                                   bf16* __restrict__ Ft,
                                                   const float* __restrict__ cw,
                                                   bf16* __restrict__ Wb,
                                                   const int* __restrict__ boxes) {
  static __shared__ __align__(16) char smem[CCH * FW * 2];   // 22528 B
  int t = threadIdx.x;
  if (blockIdx.x >= NIMG * FH) {
    int co = blockIdx.x - NIMG * FH;
    float* lw = (float*)smem;
    const float* src = cw + (long)co * CCH * 9;
    #pragma unroll
    for (int k = 0; k < 18; ++k) lw[t + 256 * k] = src[t + 256 * k];
    __syncthreads();
    bf16* dst = Wb + (long)co * 9 * CCH;
    #pragma unroll
    for (int k = 0; k < 18; ++k) {
      int f = t + 256 * k;
      int pos = f >> 9;
      int ci = f & 511;
      dst[f] = (bf16)lw[ci * 9 + pos];
    }
    return;
  }
  bf16* lt = (bf16*)smem;   // [ci][x]
  int n = blockIdx.x / FH;
  int y = blockIdx.x % FH;
  int yr0 = boxes[n * 4 + 0], yr1 = boxes[n * 4 + 1];
  if (y < yr0 || y > yr1) return;
  int xr0 = boxes[n * 4 + 2], xr1 = boxes[n * 4 + 3];
  const float* fb = feat + (long)n * CCH * SPATIAL + y * FW;
  #pragma unroll 4
  for (int k = 0; k < 44; ++k) {            // 512*22 = 11264 = 256*44
    int f = t + 256 * k;
    int ci = f / FW;
    int x = f - ci * FW;
    if (x >= xr0 && x <= xr1) lt[f] = (bf16)fb[(long)ci * SPATIAL + x];
  }
  __syncthreads();
  uint* od = (uint*)(Ft + ((long)(n * FH + y) * FW) * CCH);
  int ci = t * 2;
  for (int px = xr0; px <= xr1; ++px) {
    bf16x2 pr;
    pr[0] = lt[ci * FW + px];
    pr[1] = lt[(ci + 1) * FW + px];
    od[px * 256 + t] = __builtin_bit_cast(uint, pr);
  }
}

// ---- pool_feat: separable PrRoI pooling of features (summed over 3 images).
// Gb[N=s*16+pq][K=pos*512+ci] bf16. Grid 256 = (s 64) x (ciq 4); 512 threads:
// thread = (ci in 128, p in 4) -> per-thread acc is G4[9 pos] f32x4-over-q
// = 36 floats (round 8's 144-float acc spilled to scratch; this doesn't).
// Weight tables staged in LDS (uniform-address broadcast reads).
__global__ __launch_bounds__(512) void pool_feat_kernel(const bf16* __restrict__ Ft,
                                                        const int* __restrict__ boxes,
                                                        const float* __restrict__ wys_g,
                                                        const float* __restrict__ wxs_g,
                                                        bf16* __restrict__ Gb) {
  __shared__ float wyl[3][264];
  __shared__ float wxl[3][264];
  int s = blockIdx.x >> 2;
  int ciq = blockIdx.x & 3;
  int t = threadIdx.x;
  int p = t >> 7;                 // wave-uniform (each wave is one p half/pair)
  int lci = t & 127;
  int ci = ciq * 128 + lci;
  for (int idx = t; idx < 1584; idx += 512) {   // 3 img x (264 wy + 264 wx)
    int img = idx / 528;
    int rem = idx - img * 528;
    int n = img * 64 + s;
    if (rem < 264) wyl[img][rem] = wys_g[n * 264 + rem];
    else wxl[img][rem - 264] = wxs_g[n * 264 + rem - 264];
  }
  __syncthreads();
  f32x4 G4[9];   // [pos = ky*3+kx], vector over q; this thread's p
  #pragma unroll
  for (int a = 0; a < 9; ++a) G4[a] = (f32x4){0.f, 0.f, 0.f, 0.f};

  for (int i = 0; i < 3; ++i) {
    int n = i * 64 + s;
    int yr0 = boxes[n * 4 + 0], yr1 = boxes[n * 4 + 1];
    int xr0 = boxes[n * 4 + 2], xr1 = boxes[n * 4 + 3];
    const float* wyp = wyl[i];
    const f32x4* wxp = (const f32x4*)wxl[i];
    const bf16* fbase = Ft + (long)n * FH * FW * CCH + ci;
    for (int v = xr0; v <= xr1; ++v) {
      float ay0 = 0.f, ay1 = 0.f, ay2 = 0.f;
      const bf16* fp = fbase + v * CCH;
      for (int u = yr0; u <= yr1; ++u) {
        float f = (float)fp[(long)u * (FW * CCH)];
        ay0 = fmaf(wyp[u * 4 + p], f, ay0);
        ay1 = fmaf(wyp[(22 + u) * 4 + p], f, ay1);
        ay2 = fmaf(wyp[(44 + u) * 4 + p], f, ay2);
      }
      #pragma unroll
      for (int kx = 0; kx < 3; ++kx) {
        f32x4 wx4 = wxp[kx * 22 + v];
        G4[kx] += wx4 * ay0;
        G4[3 + kx] += wx4 * ay1;
        G4[6 + kx] += wx4 * ay2;
      }
    }
  }
  // write: Gb[(s*16 + p*4 + q)*KDIM + pos*512 + ci]
  #pragma unroll
  for (int pos = 0; pos < 9; ++pos) {
    #pragma unroll
    for (int q = 0; q < 4; ++q) {
      Gb[(long)(s * 16 + p * 4 + q) * KDIM + pos * CCH + ci] = (bf16)G4[pos][q];
    }
  }
}

// ---- gemm: Opart[kq][co 512][n 1024] += W[co][k]*Gb[n][k] over k-segment.
// 256 blocks = 4 mt x 8 nt x 8 kq; 128x128 tile, 4 waves, BK=64, 9 chunks,
// proven staging + both-sides XOR swizzle.
__global__ __launch_bounds__(256, 2) void gemm_kernel(const bf16* __restrict__ Wb,
                                                      const bf16* __restrict__ Gb,
                                                      float* __restrict__ Opart) {
  __shared__ __align__(16) bf16 As[128 * 64];
  __shared__ __align__(16) bf16 Bs[128 * 64];
  int bid = blockIdx.x;
  int kq = bid & 7;
  int nt = (bid >> 3) & 7;
  int mt = bid >> 6;
  int co0 = mt << 7;
  int n0 = nt << 7;
  int kbase = kq * KSEG;

  int tid = threadIdx.x;
  int wv = tid >> 6, l = tid & 63;
  int wm = wv >> 1, wn = wv & 1;
  int lrow = l >> 3;
  int cg8 = ((l & 7) ^ lrow) << 3;

  long aOff[4], bOff[4];
  #pragma unroll
  for (int j = 0; j < 4; ++j) {
    int row = j * 32 + wv * 8 + lrow;
    aOff[j] = (long)(co0 + row) * KDIM + kbase + cg8;
    bOff[j] = (long)(n0 + row) * KDIM + kbase + cg8;
  }

  const f32x4 vz = {0.f, 0.f, 0.f, 0.f};
  f32x4 acc[4][4];
  #pragma unroll
  for (int a = 0; a < 4; ++a)
    #pragma unroll
    for (int b = 0; b < 4; ++b) acc[a][b] = vz;

  for (int c = 0; c < 9; ++c) {
    long sh = c * 64;
    #pragma unroll
    for (int j = 0; j < 4; ++j) {
      gload_lds16(Wb + aOff[j] + sh, (char*)As + (j * 32 + wv * 8) * 128);
      gload_lds16(Gb + bOff[j] + sh, (char*)Bs + (j * 32 + wv * 8) * 128);
    }
    __syncthreads();
    bf16x8 af[2][4], bfv[2][4];
    #pragma unroll
    for (int kk = 0; kk < 2; ++kk) {
      #pragma unroll
      for (int i = 0; i < 4; ++i) {
        int rowa = wm * 64 + i * 16 + (l & 15);
        int offa = rowa * 128 + kk * 64 + ((l >> 4) * 16);
        offa ^= (rowa & 7) << 4;
        af[kk][i] = *(const bf16x8*)((const char*)As + offa);
        int rowb = wn * 64 + i * 16 + (l & 15);
        int offb = rowb * 128 + kk * 64 + ((l >> 4) * 16);
        offb ^= (rowb & 7) << 4;
        bfv[kk][i] = *(const bf16x8*)((const char*)Bs + offb);
      }
    }
    #pragma unroll
    for (int kk = 0; kk < 2; ++kk)
      #pragma unroll
      for (int mi = 0; mi < 4; ++mi)
        #pragma unroll
        for (int nj = 0; nj < 4; ++nj)
          acc[mi][nj] = __builtin_amdgcn_mfma_f32_16x16x32_bf16(
              af[kk][mi], bfv[kk][nj], acc[mi][nj], 0, 0, 0);
    __syncthreads();
  }

  // C/D layout: col=lane&15 (n), row=(lane>>4)*4+reg (co)
  float* op = Opart + (long)kq * CCH * NDIM;
  #pragma unroll
  for (int nj = 0; nj < 4; ++nj) {
    int nn = n0 + wn * 64 + nj * 16 + (l & 15);
    #pragma unroll
    for (int mi = 0; mi < 4; ++mi) {
      #pragma unroll
      for (int rr = 0; rr < 4; ++rr) {
        int co = co0 + wm * 64 + mi * 16 + (l >> 4) * 4 + rr;
        op[(long)co * NDIM + nn] = acc[mi][nj][rr];
      }
    }
  }
}

// ---- epilogue: out[s][co][pq] = (sum_kq Opart + b[co]*BF[s][pq]) * fin
__global__ __launch_bounds__(256) void epi_kernel(const float* __restrict__ Opart,
                                                  const float* __restrict__ BF,
                                                  const float* __restrict__ cb,
                                                  float* __restrict__ out) {
  int t4 = blockIdx.x * 256 + threadIdx.x;   // 131072 threads, 4 floats each
  int base = t4 * 4;                         // = s*8192 + co*16 + pqc
  int s = base >> 13;
  int co = (base >> 4) & 511;
  int pqc = base & 15;
  long osrc = (long)co * NDIM + s * 16 + pqc;
  f32x4 v = *(const f32x4*)(Opart + osrc);
  #pragma unroll
  for (int kq = 1; kq < KQ; ++kq)
    v += *(const f32x4*)(Opart + (long)kq * CCH * NDIM + osrc);
  f32x4 bf4 = *(const f32x4*)(BF + s * 16 + pqc);
  const float fin = 1.f / (3.f * 512.f * 16.f);
  v = (v + cb[co] * bf4) * fin;
  *(f32x4*)(out + base) = v;
}

extern "C" void kernel_launch(void* const* d_in, const int* in_sizes, int n_in,
                              void* d_out, int out_size, void* d_ws, size_t ws_size,
                              hipStream_t stream) {
  const float* feat = (const float*)d_in[0];
  const float* bb = (const float*)d_in[1];
  const float* cw = (const float*)d_in[2];
  const float* cb = (const float*)d_in[3];
  float* out = (float*)d_out;

  const size_t FT_BYTES = (size_t)NIMG * FH * FW * CCH * 2;     //  95,158,272
  const size_t WB_BYTES = (size_t)CCH * 9 * CCH * 2;            //   4,718,592
  const size_t GB_BYTES = (size_t)NDIM * KDIM * 2;              //   9,437,184
  const size_t OP_BYTES = (size_t)KQ * CCH * NDIM * 4;          //  16,777,216
  const size_t WT_BYTES = (size_t)NIMG * 264 * 4;               //     202,752 (x2)
  const size_t BF_BYTES = 64 * 16 * 4;
  const size_t BOX_BYTES = NIMG * 4 * 4;
  if (ws_size < FT_BYTES + WB_BYTES + GB_BYTES + OP_BYTES + 2 * WT_BYTES +
                    BF_BYTES + BOX_BYTES)
    return;

  char* ws = (char*)d_ws;
  bf16* Ft = (bf16*)ws;
  bf16* Wb = (bf16*)(ws + FT_BYTES);
  bf16* Gb = (bf16*)(ws + FT_BYTES + WB_BYTES);
  float* Opart = (float*)(ws + FT_BYTES + WB_BYTES + GB_BYTES);
  float* wys_g = (float*)(ws + FT_BYTES + WB_BYTES + GB_BYTES + OP_BYTES);
  float* wxs_g = wys_g + NIMG * 264;
  float* BF = wxs_g + NIMG * 264;
  int* boxes = (int*)(BF + 64 * 16);

  hipLaunchKernelGGL(prep_kernel, dim3(1), dim3(256), 0, stream, bb, boxes, wys_g,
                     wxs_g, BF);
  hipLaunchKernelGGL(cast_kernel, dim3(NIMG * FH + CCH), dim3(256), 0, stream,
                     feat, Ft, cw, Wb, boxes);
  hipLaunchKernelGGL(pool_feat_kernel, dim3(256), dim3(512), 0, stream, Ft, boxes,
                     wys_g, wxs_g, Gb);
  hipLaunchKernelGGL(gemm_kernel, dim3(256), dim3(256), 0, stream, Wb, Gb, Opart);
  hipLaunchKernelGGL(epi_kernel, dim3(512), dim3(256), 0, stream, Opart, BF, cb, out);
}

// Round 11
// 204.121 us; speedup vs baseline: 1.7321x; 1.6248x over previous
//
#include <hip/hip_runtime.h>

// FilterInitializerLinear: conv3x3(512->512, pad1) on (192,512,22,22) fp32,
// PrRoIPool 4x4 per (image,seq) roi, mean over 3 images, /(C*16).
// KEY ALGEBRA: pooling and conv are both linear -> pool FIRST:
//   out[s,co,pq] = (sum_K W[co,K] * G[s,K,pq] + b[co]*Sy[p]*Sx[q]) / (3*512*16)
//   G[ci,ky,kx,p,q] = sum_{u,v} wy_shift[ky][p][u] * wx_shift[kx][q][v] * F[ci][u][v]
// Round-10 fix: pool_feat was latency-bound (scalar 2B loads, 1 block/CU,
// VALUBusy 6%) -> split img into grid (768 blocks), ci-pair uint loads,
// 4-deep load batching, fp32 partials + reduce kernel.

#define NIMG 192
#define CCH 512
#define FH 22
#define FW 22
#define SPATIAL 484
#define KDIM 4608          // pos*512 + ci
#define NDIM 1024          // s*16 + p*4 + q
#define KQ 8               // K-split factor in GEMM
#define KSEG 576           // KDIM / KQ
#define PIMG 4718592L      // NDIM * KDIM (floats per img partial)

typedef __bf16 bf16;
typedef __bf16 bf16x2 __attribute__((ext_vector_type(2)));
typedef __bf16 bf16x4 __attribute__((ext_vector_type(4)));
typedef __bf16 bf16x8 __attribute__((ext_vector_type(8)));
typedef float f32x2 __attribute__((ext_vector_type(2)));
typedef float f32x4 __attribute__((ext_vector_type(4)));

#define GLOBAL_AS __attribute__((address_space(1)))
#define LDS_AS __attribute__((address_space(3)))

__device__ __forceinline__ void gload_lds16(const void* g, void* l) {
  __builtin_amdgcn_global_load_lds((GLOBAL_AS const void*)g, (LDS_AS void*)l, 16, 0, 0);
}

// ---- prep (1 block): shifted pooling-weight tables wys_g/wxs_g[n][ky][u][p]
// (fp32, zero-padded shifts), per-image read ranges boxes[n] = {yr0,yr1,xr0,xr1},
// bias factors BF[s][16] = sum_i Sy[p]*Sx[q].
__global__ __launch_bounds__(256) void prep_kernel(const float* __restrict__ bb,
                                                   int* __restrict__ boxes,
                                                   float* __restrict__ wys_g,
                                                   float* __restrict__ wxs_g,
                                                   float* __restrict__ BF) {
  __shared__ float syl[NIMG][2][4];
  int t = threadIdx.x;
  const float scale = 1.f / 16.f;
  // zero both shifted tables (contiguous in ws: wys_g then wxs_g, 101376 floats)
  f32x4* z = (f32x4*)wys_g;
  for (int idx = t; idx < 25344; idx += 256) z[idx] = (f32x4){0.f, 0.f, 0.f, 0.f};
  if (t < NIMG) {
    int n = t;
    float x1s = bb[n * 4 + 0] * scale;
    float y1s = bb[n * 4 + 1] * scale;
    float x2s = (bb[n * 4 + 0] + bb[n * 4 + 2]) * scale;
    float y2s = (bb[n * 4 + 1] + bb[n * 4 + 3]) * scale;
    float binx = (x2s - x1s) * 0.25f;
    float biny = (y2s - y1s) * 0.25f;
    float endx = (x1s + 3 * binx) + binx;   // fp-identical to weight-fill bin-3 end
    float endy = (y1s + 3 * biny) + biny;
    int x0 = max(0, (int)floorf(x1s));
    int xc1 = min(FW - 1, (int)floorf(endx) + 1);
    int y0 = max(0, (int)floorf(y1s));
    int yc1 = min(FH - 1, (int)floorf(endy) + 1);
    int* b = boxes + n * 4;
    b[0] = max(0, y0 - 1);       // u-range (support of shifted wy)
    b[1] = min(FH - 1, yc1 + 1);
    b[2] = max(0, x0 - 1);       // v-range
    b[3] = min(FW - 1, xc1 + 1);
  }
  __syncthreads();
  // weight fill: item = (n, axis, p); each item owns distinct table entries
  #pragma unroll
  for (int k = 0; k < 6; ++k) {
    int item = t + 256 * k;   // < 1536
    int n = item >> 3;
    int axis = (item >> 2) & 1;
    int p = item & 3;
    float a0 = axis ? bb[n * 4 + 0] : bb[n * 4 + 1];
    float aw = axis ? bb[n * 4 + 2] : bb[n * 4 + 3];
    float s1 = a0 * scale;
    float s2 = (a0 + aw) * scale;
    float blen = (s2 - s1) * 0.25f;
    float start = s1 + p * blen;
    float end = start + blen;
    float inv = 1.0f / blen;           // folds 1/area
    float* tbl = (axis ? wxs_g : wys_g) + n * 264;   // [3ky][22u][4p]
    float S = 0.f;
    int s0i = (int)floorf(start);
    for (int kk = 0; kk < 6; ++kk) {
      int cell = s0i + kk;
      float cf = (float)cell;
      float a1 = fmaxf(start, cf);
      float a2 = fmaxf(fminf(end, cf + 1.f), a1);
      float alpha = a1 - cf, lim = a2 - cf;
      float f0 = (lim - 0.5f * lim * lim) - (alpha - 0.5f * alpha * alpha);
      float f1 = 0.5f * lim * lim - 0.5f * alpha * alpha;
      if (cell >= 0 && cell < 22) {
        float w = f0 * inv;
        S += w;
        #pragma unroll
        for (int ky = 0; ky < 3; ++ky) {
          int u = cell + ky - 1;
          if (u >= 0 && u < 22) tbl[(ky * 22 + u) * 4 + p] += w;
        }
      }
      if (cell + 1 >= 0 && cell + 1 < 22) {
        float w = f1 * inv;
        S += w;
        #pragma unroll
        for (int ky = 0; ky < 3; ++ky) {
          int u = cell + ky;
          if (u >= 0 && u < 22) tbl[(ky * 22 + u) * 4 + p] += w;
        }
      }
    }
    syl[n][axis][p] = S;
  }
  __syncthreads();
  #pragma unroll
  for (int k = 0; k < 4; ++k) {
    int item = t + 256 * k;   // < 1024 = s*16 + p*4 + q
    int s = item >> 4;
    int p = (item >> 2) & 3;
    int q = item & 3;
    float acc = 0.f;
    #pragma unroll
    for (int i = 0; i < 3; ++i)
      acc += syl[i * 64 + s][0][p] * syl[i * 64 + s][1][q];
    BF[item] = acc;
  }
}

// ---- cast: feat fp32 NCHW -> bf16 NHWC Ft[n][y][x][ci], restricted to the
// box read ranges. Fused: blocks [NIMG*FH, +CCH) do conv_w -> Wb[co][pos][ci].
__global__ __launch_bounds__(256) void cast_kernel(const float* __restrict__ feat,
                                                   bf16* __restrict__ Ft,
                                                   const float* __restrict__ cw,
                                                   bf16* __restrict__ Wb,
                                                   const int* __restrict__ boxes) {
  static __shared__ __align__(16) char smem[CCH * FW * 2];   // 22528 B
  int t = threadIdx.x;
  if (blockIdx.x >= NIMG * FH) {
    int co = blockIdx.x - NIMG * FH;
    float* lw = (float*)smem;
    const float* src = cw + (long)co * CCH * 9;
    #pragma unroll
    for (int k = 0; k < 18; ++k) lw[t + 256 * k] = src[t + 256 * k];
    __syncthreads();
    bf16* dst = Wb + (long)co * 9 * CCH;
    #pragma unroll
    for (int k = 0; k < 18; ++k) {
      int f = t + 256 * k;
      int pos = f >> 9;
      int ci = f & 511;
      dst[f] = (bf16)lw[ci * 9 + pos];
    }
    return;
  }
  bf16* lt = (bf16*)smem;   // [ci][x]
  int n = blockIdx.x / FH;
  int y = blockIdx.x % FH;
  int yr0 = boxes[n * 4 + 0], yr1 = boxes[n * 4 + 1];
  if (y < yr0 || y > yr1) return;
  int xr0 = boxes[n * 4 + 2], xr1 = boxes[n * 4 + 3];
  const float* fb = feat + (long)n * CCH * SPATIAL + y * FW;
  #pragma unroll 4
  for (int k = 0; k < 44; ++k) {            // 512*22 = 11264 = 256*44
    int f = t + 256 * k;
    int ci = f / FW;
    int x = f - ci * FW;
    if (x >= xr0 && x <= xr1) lt[f] = (bf16)fb[(long)ci * SPATIAL + x];
  }
  __syncthreads();
  uint* od = (uint*)(Ft + ((long)(n * FH + y) * FW) * CCH);
  int ci = t * 2;
  for (int px = xr0; px <= xr1; ++px) {
    bf16x2 pr;
    pr[0] = lt[ci * FW + px];
    pr[1] = lt[(ci + 1) * FW + px];
    od[px * 256 + t] = __builtin_bit_cast(uint, pr);
  }
}

// ---- pool_feat: separable PrRoI pooling of features, per image ->
// Gpart[img][N=s*16+pq][K=pos*512+ci] fp32.
// Grid 768 = (s 64) x (ciq 4) x (img 3); 256 threads = (lci 64, p 4);
// lane owns a ci PAIR (uint load = 256B/wave), u-loop 4-deep load batching.
// Per-thread acc = 2x f32x4[9] = 72 floats (no spill; bounds(256,3)).
__global__ __launch_bounds__(256, 3) void pool_feat_kernel(
    const bf16* __restrict__ Ft, const int* __restrict__ boxes,
    const float* __restrict__ wys_g, const float* __restrict__ wxs_g,
    float* __restrict__ Gpart) {
  __shared__ float wyl[264];
  __shared__ float wxl[264];
  int bid = blockIdx.x;
  int img = bid % 3;
  int rest = bid / 3;
  int ciq = rest & 3;
  int s = rest >> 2;
  int n = img * 64 + s;
  int t = threadIdx.x;
  int p = t >> 6;                 // wave-uniform
  int lci = t & 63;
  int ci = ciq * 128 + lci * 2;
  for (int idx = t; idx < 528; idx += 256) {
    if (idx < 264) wyl[idx] = wys_g[n * 264 + idx];
    else wxl[idx - 264] = wxs_g[n * 264 + idx - 264];
  }
  __syncthreads();
  int yr0 = boxes[n * 4 + 0], yr1 = boxes[n * 4 + 1];
  int xr0 = boxes[n * 4 + 2], xr1 = boxes[n * 4 + 3];

  f32x4 A0[9], A1[9];   // [pos = ky*3+kx] over q; A0 = ci, A1 = ci+1
  #pragma unroll
  for (int a = 0; a < 9; ++a) {
    A0[a] = (f32x4){0.f, 0.f, 0.f, 0.f};
    A1[a] = (f32x4){0.f, 0.f, 0.f, 0.f};
  }

  // Ft as uint (ci pairs): elem (u,v) at [(u*FW+v)*256 + ciq*64 + lci]
  const uint* base = (const uint*)Ft + (long)n * FH * FW * 256 + ciq * 64 + lci;
  const f32x4* wxp = (const f32x4*)wxl;

#define PROC(BU, UU)                                                     \
  {                                                                      \
    bf16x2 pr = __builtin_bit_cast(bf16x2, (BU));                        \
    float f0 = (float)pr[0], f1 = (float)pr[1];                          \
    float w0 = wyl[(UU) * 4 + p];                                        \
    float w1 = wyl[(22 + (UU)) * 4 + p];                                 \
    float w2 = wyl[(44 + (UU)) * 4 + p];                                 \
    a00 = fmaf(w0, f0, a00); a01 = fmaf(w0, f1, a01);                    \
    a10 = fmaf(w1, f0, a10); a11 = fmaf(w1, f1, a11);                    \
    a20 = fmaf(w2, f0, a20); a21 = fmaf(w2, f1, a21);                    \
  }

  for (int v = xr0; v <= xr1; ++v) {
    const uint* colp = base + v * 256;
    float a00 = 0.f, a01 = 0.f, a10 = 0.f, a11 = 0.f, a20 = 0.f, a21 = 0.f;
    int u = yr0;
    for (; u + 3 <= yr1; u += 4) {          // 4 independent loads in flight
      uint b0 = colp[(long)u * 5632];
      uint b1 = colp[(long)(u + 1) * 5632];
      uint b2 = colp[(long)(u + 2) * 5632];
      uint b3 = colp[(long)(u + 3) * 5632];
      PROC(b0, u); PROC(b1, u + 1); PROC(b2, u + 2); PROC(b3, u + 3);
    }
    for (; u <= yr1; ++u) {
      uint b0 = colp[(long)u * 5632];
      PROC(b0, u);
    }
    #pragma unroll
    for (int kx = 0; kx < 3; ++kx) {
      f32x4 wx4 = wxp[kx * 22 + v];
      A0[kx] += wx4 * a00; A1[kx] += wx4 * a01;
      A0[3 + kx] += wx4 * a10; A1[3 + kx] += wx4 * a11;
      A0[6 + kx] += wx4 * a20; A1[6 + kx] += wx4 * a21;
    }
  }
#undef PROC

  float* gp = Gpart + (long)img * PIMG;
  #pragma unroll
  for (int pos = 0; pos < 9; ++pos) {
    #pragma unroll
    for (int q = 0; q < 4; ++q) {
      long off = (long)(s * 16 + p * 4 + q) * KDIM + pos * CCH + ci;
      f32x2 w2 = {A0[pos][q], A1[pos][q]};
      *(f32x2*)(gp + off) = w2;
    }
  }
}

// ---- reduce: Gb = bf16(Gpart[0] + Gpart[1] + Gpart[2])
__global__ __launch_bounds__(256) void reduce_kernel(const float* __restrict__ Gp,
                                                     bf16* __restrict__ Gb) {
  long i = ((long)blockIdx.x * 256 + threadIdx.x) * 4;
  f32x4 v = *(const f32x4*)(Gp + i);
  v += *(const f32x4*)(Gp + PIMG + i);
  v += *(const f32x4*)(Gp + 2 * PIMG + i);
  bf16x4 o;
  #pragma unroll
  for (int j = 0; j < 4; ++j) o[j] = (bf16)v[j];
  *(bf16x4*)(Gb + i) = o;
}

// ---- gemm: Opart[kq][co 512][n 1024] += W[co][k]*Gb[n][k] over k-segment.
// 256 blocks = 4 mt x 8 nt x 8 kq; 128x128 tile, 4 waves, BK=64, 9 chunks,
// proven staging + both-sides XOR swizzle.
__global__ __launch_bounds__(256, 2) void gemm_kernel(const bf16* __restrict__ Wb,
                                                      const bf16* __restrict__ Gb,
                                                      float* __restrict__ Opart) {
  __shared__ __align__(16) bf16 As[128 * 64];
  __shared__ __align__(16) bf16 Bs[128 * 64];
  int bid = blockIdx.x;
  int kq = bid & 7;
  int nt = (bid >> 3) & 7;
  int mt = bid >> 6;
  int co0 = mt << 7;
  int n0 = nt << 7;
  int kbase = kq * KSEG;

  int tid = threadIdx.x;
  int wv = tid >> 6, l = tid & 63;
  int wm = wv >> 1, wn = wv & 1;
  int lrow = l >> 3;
  int cg8 = ((l & 7) ^ lrow) << 3;

  long aOff[4], bOff[4];
  #pragma unroll
  for (int j = 0; j < 4; ++j) {
    int row = j * 32 + wv * 8 + lrow;
    aOff[j] = (long)(co0 + row) * KDIM + kbase + cg8;
    bOff[j] = (long)(n0 + row) * KDIM + kbase + cg8;
  }

  const f32x4 vz = {0.f, 0.f, 0.f, 0.f};
  f32x4 acc[4][4];
  #pragma unroll
  for (int a = 0; a < 4; ++a)
    #pragma unroll
    for (int b = 0; b < 4; ++b) acc[a][b] = vz;

  for (int c = 0; c < 9; ++c) {
    long sh = c * 64;
    #pragma unroll
    for (int j = 0; j < 4; ++j) {
      gload_lds16(Wb + aOff[j] + sh, (char*)As + (j * 32 + wv * 8) * 128);
      gload_lds16(Gb + bOff[j] + sh, (char*)Bs + (j * 32 + wv * 8) * 128);
    }
    __syncthreads();
    bf16x8 af[2][4], bfv[2][4];
    #pragma unroll
    for (int kk = 0; kk < 2; ++kk) {
      #pragma unroll
      for (int i = 0; i < 4; ++i) {
        int rowa = wm * 64 + i * 16 + (l & 15);
        int offa = rowa * 128 + kk * 64 + ((l >> 4) * 16);
        offa ^= (rowa & 7) << 4;
        af[kk][i] = *(const bf16x8*)((const char*)As + offa);
        int rowb = wn * 64 + i * 16 + (l & 15);
        int offb = rowb * 128 + kk * 64 + ((l >> 4) * 16);
        offb ^= (rowb & 7) << 4;
        bfv[kk][i] = *(const bf16x8*)((const char*)Bs + offb);
      }
    }
    #pragma unroll
    for (int kk = 0; kk < 2; ++kk)
      #pragma unroll
      for (int mi = 0; mi < 4; ++mi)
        #pragma unroll
        for (int nj = 0; nj < 4; ++nj)
          acc[mi][nj] = __builtin_amdgcn_mfma_f32_16x16x32_bf16(
              af[kk][mi], bfv[kk][nj], acc[mi][nj], 0, 0, 0);
    __syncthreads();
  }

  // C/D layout: col=lane&15 (n), row=(lane>>4)*4+reg (co)
  float* op = Opart + (long)kq * CCH * NDIM;
  #pragma unroll
  for (int nj = 0; nj < 4; ++nj) {
    int nn = n0 + wn * 64 + nj * 16 + (l & 15);
    #pragma unroll
    for (int mi = 0; mi < 4; ++mi) {
      #pragma unroll
      for (int rr = 0; rr < 4; ++rr) {
        int co = co0 + wm * 64 + mi * 16 + (l >> 4) * 4 + rr;
        op[(long)co * NDIM + nn] = acc[mi][nj][rr];
      }
    }
  }
}

// ---- epilogue: out[s][co][pq] = (sum_kq Opart + b[co]*BF[s][pq]) * fin
__global__ __launch_bounds__(256) void epi_kernel(const float* __restrict__ Opart,
                                                  const float* __restrict__ BF,
                                                  const float* __restrict__ cb,
                                                  float* __restrict__ out) {
  int t4 = blockIdx.x * 256 + threadIdx.x;   // 131072 threads, 4 floats each
  int base = t4 * 4;                         // = s*8192 + co*16 + pqc
  int s = base >> 13;
  int co = (base >> 4) & 511;
  int pqc = base & 15;
  long osrc = (long)co * NDIM + s * 16 + pqc;
  f32x4 v = *(const f32x4*)(Opart + osrc);
  #pragma unroll
  for (int kq = 1; kq < KQ; ++kq)
    v += *(const f32x4*)(Opart + (long)kq * CCH * NDIM + osrc);
  f32x4 bf4 = *(const f32x4*)(BF + s * 16 + pqc);
  const float fin = 1.f / (3.f * 512.f * 16.f);
  v = (v + cb[co] * bf4) * fin;
  *(f32x4*)(out + base) = v;
}

extern "C" void kernel_launch(void* const* d_in, const int* in_sizes, int n_in,
                              void* d_out, int out_size, void* d_ws, size_t ws_size,
                              hipStream_t stream) {
  const float* feat = (const float*)d_in[0];
  const float* bb = (const float*)d_in[1];
  const float* cw = (const float*)d_in[2];
  const float* cb = (const float*)d_in[3];
  float* out = (float*)d_out;

  const size_t FT_BYTES = (size_t)NIMG * FH * FW * CCH * 2;     //  95,158,272
  const size_t WB_BYTES = (size_t)CCH * 9 * CCH * 2;            //   4,718,592
  const size_t GB_BYTES = (size_t)NDIM * KDIM * 2;              //   9,437,184
  const size_t OP_BYTES = (size_t)KQ * CCH * NDIM * 4;          //  16,777,216
  const size_t GP_BYTES = (size_t)3 * PIMG * 4;                 //  56,623,104
  const size_t WT_BYTES = (size_t)NIMG * 264 * 4;               //     202,752 (x2)
  const size_t BF_BYTES = 64 * 16 * 4;
  const size_t BOX_BYTES = NIMG * 4 * 4;
  if (ws_size < FT_BYTES + WB_BYTES + GB_BYTES + OP_BYTES + GP_BYTES +
                    2 * WT_BYTES + BF_BYTES + BOX_BYTES)
    return;

  char* ws = (char*)d_ws;
  bf16* Ft = (bf16*)ws;
  bf16* Wb = (bf16*)(ws + FT_BYTES);
  bf16* Gb = (bf16*)(ws + FT_BYTES + WB_BYTES);
  float* Opart = (float*)(ws + FT_BYTES + WB_BYTES + GB_BYTES);
  float* Gpart = (float*)(ws + FT_BYTES + WB_BYTES + GB_BYTES + OP_BYTES);
  float* wys_g = (float*)(ws + FT_BYTES + WB_BYTES + GB_BYTES + OP_BYTES + GP_BYTES);
  float* wxs_g = wys_g + NIMG * 264;
  float* BF = wxs_g + NIMG * 264;
  int* boxes = (int*)(BF + 64 * 16);

  hipLaunchKernelGGL(prep_kernel, dim3(1), dim3(256), 0, stream, bb, boxes, wys_g,
                     wxs_g, BF);
  hipLaunchKernelGGL(cast_kernel, dim3(NIMG * FH + CCH), dim3(256), 0, stream,
                     feat, Ft, cw, Wb, boxes);
  hipLaunchKernelGGL(pool_feat_kernel, dim3(768), dim3(256), 0, stream, Ft, boxes,
                     wys_g, wxs_g, Gpart);
  hipLaunchKernelGGL(reduce_kernel, dim3(4608), dim3(256), 0, stream, Gpart, Gb);
  hipLaunchKernelGGL(gemm_kernel, dim3(256), dim3(256), 0, stream, Wb, Gb, Opart);
  hipLaunchKernelGGL(epi_kernel, dim3(512), dim3(256), 0, stream, Opart, BF, cb, out);
}